// Round 2
// baseline (1420.331 us; speedup 1.0000x reference)
//
#include <hip/hip_runtime.h>

// 3x3 stride-1 VALID conv, NCHW fp32 in/out, bf16 MFMA implicit GEMM.
// N=16, Cin=Cout=32, 512x512 -> 510x510.
// D[m=co][n=pixel], K=ci (32 = one MFMA K), 9 taps accumulate.
// Wave split: wv = (co-half, x-half) -> only 9 A-frags live per wave (36 VGPR),
// enabling 6 blocks/CU (24 waves) with RT=3 (23.8 KB LDS).
// Weights pre-formatted to bf16 A-fragments in d_ws by a prep kernel.

namespace {
constexpr int NI    = 16;
constexpr int C_IN  = 32;
constexpr int HI    = 512;
constexpr int WI    = 512;
constexpr int C_OUT = 32;
constexpr int HO    = 510;
constexpr int WO    = 510;

constexpr int RT    = 3;        // output rows per block (510/3 = 170 exact)
constexpr int PT    = 64;       // output x-pixels per block
constexpr int XROWS = RT + 2;   // 5 staged input rows
constexpr int XCOLS = PT + 2;   // 66 staged input cols
constexpr int PSTR  = 36;       // shorts per pixel (72B stride, measured conflict-free)
constexpr int HIWI  = HI * WI;
}

typedef __attribute__((ext_vector_type(4))) float  floatx4;
typedef __attribute__((ext_vector_type(8))) __bf16 bf16x8;
typedef __attribute__((ext_vector_type(4))) __bf16 bf16x4;
typedef __attribute__((ext_vector_type(4))) unsigned short ushortx4;

// ---- weight prep: w [co][ci][3][3] f32 -> ws bf16 A-fragments [tap][h][lane][j]
// lane = quad*16 + l16; element j: co = h*16 + l16, ci = quad*8 + j.
__global__ void conv_wprep(const float* __restrict__ w, __bf16* __restrict__ ws) {
  const int t = threadIdx.x;
  for (int i = t; i < 9 * 2 * 64 * 8; i += 256) {
    const int j    = i & 7;
    const int lane = (i >> 3) & 63;
    const int h    = (i >> 9) & 1;
    const int tap  = i >> 10;
    const int co   = h * 16 + (lane & 15);
    const int ci   = (lane >> 4) * 8 + j;
    ws[i] = (__bf16)w[(co * C_IN + ci) * 9 + tap];
  }
}

__global__ __launch_bounds__(256, 6)
void conv3x3_mfma(const float* __restrict__ x, const __bf16* __restrict__ ws,
                  const float* __restrict__ bias, float* __restrict__ out) {
  __shared__ unsigned short lds[XROWS * XCOLS * PSTR];  // 23760 B -> 6 blocks/CU

  const int t    = threadIdx.x;
  const int lane = t & 63;
  const int wv   = t >> 6;
  const int quad = lane >> 4;
  const int l16  = lane & 15;
  const int xh   = wv & 1;        // x-half: pixels [xh*32, xh*32+32)
  const int ch   = wv >> 1;       // co-half: channels [ch*16, ch*16+16)

  const int x0 = blockIdx.x * PT;
  const int y0 = blockIdx.y * RT;
  const int n  = blockIdx.z;

  // ---- stage X tile: 330 pixels x 32 ci. One pixel per lane-iteration:
  // per ci the wave's 64 loads are 64 consecutive floats (coalesced dwords);
  // pack 32 bf16 in regs, then 8x ds_write_b64 (72B lane stride = bank-minimum).
  for (int p = t; p < XROWS * XCOLS; p += 256) {
    const int row = p / XCOLS;
    const int col = p - row * XCOLS;
    int gx = x0 + col;
    if (gx > WI - 1) gx = WI - 1;   // clamp last tile's halo (values unused by valid outputs)
    const float* xp = x + ((size_t)(n * C_IN) * HI + (y0 + row)) * WI + gx;
    union { __bf16 b[32]; ushortx4 q[8]; } pk;
#pragma unroll
    for (int ci = 0; ci < C_IN; ++ci)
      pk.b[ci] = (__bf16)xp[ci * HIWI];
    unsigned short* dst = &lds[p * PSTR];
#pragma unroll
    for (int k = 0; k < 8; ++k)
      *reinterpret_cast<ushortx4*>(dst + k * 4) = pk.q[k];
  }

  // ---- A fragments: 9 coalesced 16B loads from prepped ws (L2-resident).
  // Lane holds W[co = ch*16 + l16][ci = quad*8 + j] for each tap.
  bf16x8 afrag[9];
#pragma unroll
  for (int tap = 0; tap < 9; ++tap)
    afrag[tap] = *reinterpret_cast<const bf16x8*>(ws + ((tap * 2 + ch) * 64 + lane) * 8);

  // bias per accumulator register: D row (m) = quad*4 + r -> co = ch*16 + quad*4 + r
  float bv[4];
#pragma unroll
  for (int r = 0; r < 4; ++r)
    bv[r] = bias[ch * 16 + quad * 4 + r];

  __syncthreads();

  const int p0  = xh * 32 + l16;       // B col n = l16, first px-group
  const int px0 = x0 + p0;             // always < 496 -> always valid
  const int px1 = px0 + 16;
  const bool valid1 = px1 < WO;

  for (int row = 0; row < RT; ++row) {
    floatx4 acc0 = {bv[0], bv[1], bv[2], bv[3]};
    floatx4 acc1 = {bv[0], bv[1], bv[2], bv[3]};
#pragma unroll
    for (int ky = 0; ky < 3; ++ky)
#pragma unroll
      for (int kx = 0; kx < 3; ++kx) {
        // B: lane holds X[ci = quad*8 + j][pixel] ; two px-groups per wave.
        // 72B stride is 8B-aligned only -> read as two b64 halves (bank-minimum).
        const int base0 = ((row + ky) * XCOLS + p0 + kx) * PSTR + quad * 8;
        union { bf16x8 v; bf16x4 h[2]; } bf0, bf1;
        bf0.h[0] = *reinterpret_cast<const bf16x4*>(&lds[base0]);
        bf0.h[1] = *reinterpret_cast<const bf16x4*>(&lds[base0 + 4]);
        bf1.h[0] = *reinterpret_cast<const bf16x4*>(&lds[base0 + 16 * PSTR]);
        bf1.h[1] = *reinterpret_cast<const bf16x4*>(&lds[base0 + 16 * PSTR + 4]);
        acc0 = __builtin_amdgcn_mfma_f32_16x16x32_bf16(afrag[ky * 3 + kx], bf0.v, acc0, 0, 0, 0);
        acc1 = __builtin_amdgcn_mfma_f32_16x16x32_bf16(afrag[ky * 3 + kx], bf1.v, acc1, 0, 0, 0);
      }
    float* op = out + ((size_t)(n * C_OUT + ch * 16 + quad * 4) * HO + (y0 + row)) * WO;
#pragma unroll
    for (int r = 0; r < 4; ++r) {
      op[r * (HO * WO) + px0] = acc0[r];            // co = ch*16 + quad*4 + r
      if (valid1) op[r * (HO * WO) + px1] = acc1[r];
    }
  }
}

extern "C" void kernel_launch(void* const* d_in, const int* in_sizes, int n_in,
                              void* d_out, int out_size, void* d_ws, size_t ws_size,
                              hipStream_t stream) {
  const float* x    = (const float*)d_in[0];
  const float* w    = (const float*)d_in[1];
  const float* bias = (const float*)d_in[2];
  float* out        = (float*)d_out;
  __bf16* ws        = (__bf16*)d_ws;          // needs 18432 B

  conv_wprep<<<dim3(1), 256, 0, stream>>>(w, ws);

  dim3 grid(WI / PT, HO / RT, NI);  // 8 x 170 x 16 = 21760 blocks, 256 threads
  conv3x3_mfma<<<grid, 256, 0, stream>>>(x, ws, bias, out);
}

// Round 3
// 1259.005 us; speedup vs baseline: 1.1281x; 1.1281x over previous
//
#include <hip/hip_runtime.h>

// 3x3 stride-1 VALID conv, NCHW fp32 in/out, bf16 MFMA implicit GEMM.
// N=16, Cin=Cout=32, 512x512 -> 510x510.
// D[m=co][n=pixel], K=ci (32 = one MFMA K), 9 taps accumulate.
// R1 tile geometry (RT=6, PT=64: traffic-optimal, 1.08 GB HBM) but 512 threads:
// 8 waves/block, wave = (co-half, x-quarter) -> 9 A-frags + 1 acc per wave
// (~45 VGPR), 4 blocks/CU x 8 waves = 32 waves/CU = 100% occupancy cap.
// Weights pre-formatted to bf16 A-fragments in d_ws by a prep kernel.

namespace {
constexpr int NI    = 16;
constexpr int C_IN  = 32;
constexpr int HI    = 512;
constexpr int WI    = 512;
constexpr int C_OUT = 32;
constexpr int HO    = 510;
constexpr int WO    = 510;

constexpr int RT    = 6;        // output rows per block (510/6 = 85 exact)
constexpr int PT    = 64;       // output x-pixels per block
constexpr int XROWS = RT + 2;   // 8 staged input rows
constexpr int XCOLS = PT + 2;   // 66 staged input cols
constexpr int PSTR  = 36;       // shorts per pixel (72B stride, measured conflict-free)
constexpr int HIWI  = HI * WI;
constexpr int NT    = 512;      // threads per block
}

typedef __attribute__((ext_vector_type(4))) float  floatx4;
typedef __attribute__((ext_vector_type(8))) __bf16 bf16x8;
typedef __attribute__((ext_vector_type(4))) __bf16 bf16x4;
typedef __attribute__((ext_vector_type(4))) unsigned short ushortx4;

// ---- weight prep: w [co][ci][3][3] f32 -> ws bf16 A-fragments [tap][h][lane][j]
// lane = quad*16 + l16; element j: co = h*16 + l16, ci = quad*8 + j.
__global__ void conv_wprep(const float* __restrict__ w, __bf16* __restrict__ ws) {
  const int t = threadIdx.x;
  for (int i = t; i < 9 * 2 * 64 * 8; i += 256) {
    const int j    = i & 7;
    const int lane = (i >> 3) & 63;
    const int h    = (i >> 9) & 1;
    const int tap  = i >> 10;
    const int co   = h * 16 + (lane & 15);
    const int ci   = (lane >> 4) * 8 + j;
    ws[i] = (__bf16)w[(co * C_IN + ci) * 9 + tap];
  }
}

__global__ __launch_bounds__(NT, 8)
void conv3x3_mfma(const float* __restrict__ x, const __bf16* __restrict__ ws,
                  const float* __restrict__ bias, float* __restrict__ out) {
  __shared__ unsigned short lds[XROWS * XCOLS * PSTR];  // 38016 B -> 4 blocks/CU

  const int t    = threadIdx.x;
  const int lane = t & 63;
  const int wv   = t >> 6;        // 0..7
  const int quad = lane >> 4;
  const int l16  = lane & 15;
  const int ch   = wv >> 2;       // co-half: channels [ch*16, ch*16+16)
  const int xq   = wv & 3;        // x-quarter: pixels [xq*16, xq*16+16)

  const int x0 = blockIdx.x * PT;
  const int y0 = blockIdx.y * RT;
  const int n  = blockIdx.z;

  // ---- stage X tile: 528 pixels x 32 ci. One pixel per lane-iteration:
  // per ci the wave's 64 loads are 64 consecutive floats (coalesced dwords);
  // pack 32 bf16 in regs, then 8x ds_write_b64 (72B lane stride = bank-minimum).
  for (int p = t; p < XROWS * XCOLS; p += NT) {
    const int row = p / XCOLS;
    const int col = p - row * XCOLS;
    int gx = x0 + col;
    if (gx > WI - 1) gx = WI - 1;   // clamp last tile's halo (values unused by valid outputs)
    const float* xp = x + ((size_t)(n * C_IN) * HI + (y0 + row)) * WI + gx;
    union { __bf16 b[32]; ushortx4 q[8]; } pk;
#pragma unroll
    for (int ci = 0; ci < C_IN; ++ci)
      pk.b[ci] = (__bf16)xp[ci * HIWI];
    unsigned short* dst = &lds[p * PSTR];
#pragma unroll
    for (int k = 0; k < 8; ++k)
      *reinterpret_cast<ushortx4*>(dst + k * 4) = pk.q[k];
  }

  // ---- A fragments: 9 coalesced 16B loads from prepped ws (L2-resident).
  // Lane holds W[co = ch*16 + l16][ci = quad*8 + j] for each tap.
  bf16x8 afrag[9];
#pragma unroll
  for (int tap = 0; tap < 9; ++tap)
    afrag[tap] = *reinterpret_cast<const bf16x8*>(ws + ((tap * 2 + ch) * 64 + lane) * 8);

  // bias per accumulator register: D row (m) = quad*4 + r -> co = ch*16 + quad*4 + r
  float bv[4];
#pragma unroll
  for (int r = 0; r < 4; ++r)
    bv[r] = bias[ch * 16 + quad * 4 + r];

  __syncthreads();

  const int p0  = xq * 16 + l16;       // B col n = l16
  const int px  = x0 + p0;
  const bool valid = px < WO;          // only xq==3 group at last x-block can fail

  for (int row = 0; row < RT; ++row) {
    floatx4 acc = {bv[0], bv[1], bv[2], bv[3]};
#pragma unroll
    for (int ky = 0; ky < 3; ++ky)
#pragma unroll
      for (int kx = 0; kx < 3; ++kx) {
        // B: lane holds X[ci = quad*8 + j][pixel = p0 + kx] at row row+ky.
        // 72B stride is 8B-aligned only -> read as two b64 halves (bank-minimum).
        const int base = ((row + ky) * XCOLS + p0 + kx) * PSTR + quad * 8;
        union { bf16x8 v; bf16x4 h[2]; } bf;
        bf.h[0] = *reinterpret_cast<const bf16x4*>(&lds[base]);
        bf.h[1] = *reinterpret_cast<const bf16x4*>(&lds[base + 4]);
        acc = __builtin_amdgcn_mfma_f32_16x16x32_bf16(afrag[ky * 3 + kx], bf.v, acc, 0, 0, 0);
      }
    if (valid) {
      float* op = out + ((size_t)(n * C_OUT + ch * 16 + quad * 4) * HO + (y0 + row)) * WO + px;
#pragma unroll
      for (int r = 0; r < 4; ++r)
        op[r * (HO * WO)] = acc[r];     // co = ch*16 + quad*4 + r
    }
  }
}

extern "C" void kernel_launch(void* const* d_in, const int* in_sizes, int n_in,
                              void* d_out, int out_size, void* d_ws, size_t ws_size,
                              hipStream_t stream) {
  const float* x    = (const float*)d_in[0];
  const float* w    = (const float*)d_in[1];
  const float* bias = (const float*)d_in[2];
  float* out        = (float*)d_out;
  __bf16* ws        = (__bf16*)d_ws;          // needs 18432 B

  conv_wprep<<<dim3(1), 256, 0, stream>>>(w, ws);

  dim3 grid(WI / PT, HO / RT, NI);  // 8 x 85 x 16 = 10880 blocks, 512 threads
  conv3x3_mfma<<<grid, NT, 0, stream>>>(x, ws, bias, out);
}

// Round 4
// 1027.503 us; speedup vs baseline: 1.3823x; 1.2253x over previous
//
#include <hip/hip_runtime.h>

// 3x3 stride-1 VALID conv, NCHW fp32 in/out, bf16 MFMA implicit GEMM.
// N=16, Cin=Cout=32, 512x512 -> 510x510.
// D[m=co][n=pixel], K=ci (32 = one MFMA K), 9 taps accumulate.
// R1 tile (RT=6, PT=64) = traffic-optimal. This round: ring-buffer LDS
// (4 row slots, 19 KB) with per-row staging overlapped with compute,
// wave = (co-half, x-half) so only 9 A-frags (36 regs)/wave, and
// __launch_bounds__(256,6) sized to stay SPILL-FREE (R2/R3 regressions
// were staging-buffer scratch spills: +368 MB fetch+write each).

namespace {
constexpr int NI    = 16;
constexpr int C_IN  = 32;
constexpr int HI    = 512;
constexpr int WI    = 512;
constexpr int C_OUT = 32;
constexpr int HO    = 510;
constexpr int WO    = 510;

constexpr int RT    = 6;        // output rows per block (510/6 = 85 exact)
constexpr int PT    = 64;       // output x-pixels per block
constexpr int RBUF  = 4;        // LDS ring slots (rows)
constexpr int XCOLS = PT + 2;   // 66 staged input cols
constexpr int PSTR  = 36;       // shorts per pixel (72B stride, measured conflict-free)
constexpr int HIWI  = HI * WI;
constexpr int NT    = 256;
constexpr int UNITS = XCOLS * 4;  // 264 stage units per row: (px, ci-octet)
}

typedef __attribute__((ext_vector_type(4))) float  floatx4;
typedef __attribute__((ext_vector_type(8))) __bf16 bf16x8;
typedef __attribute__((ext_vector_type(4))) __bf16 bf16x4;
typedef __attribute__((ext_vector_type(4))) unsigned short ushortx4;

// ---- weight prep: w [co][ci][3][3] f32 -> ws bf16 A-fragments [tap][h][lane][j]
// lane = quad*16 + l16; element j: co = h*16 + l16, ci = quad*8 + j.
__global__ void conv_wprep(const float* __restrict__ w, __bf16* __restrict__ ws) {
  const int t = threadIdx.x;
  for (int i = t; i < 9 * 2 * 64 * 8; i += 256) {
    const int j    = i & 7;
    const int lane = (i >> 3) & 63;
    const int h    = (i >> 9) & 1;
    const int tap  = i >> 10;
    const int co   = h * 16 + (lane & 15);
    const int ci   = (lane >> 4) * 8 + j;
    ws[i] = (__bf16)w[(co * C_IN + ci) * 9 + tap];
  }
}

__global__ __launch_bounds__(NT, 6)
void conv3x3_mfma(const float* __restrict__ x, const __bf16* __restrict__ ws,
                  const float* __restrict__ bias, float* __restrict__ out) {
  __shared__ unsigned short lds[RBUF * XCOLS * PSTR];  // 19008 B

  const int t    = threadIdx.x;
  const int lane = t & 63;
  const int wv   = t >> 6;        // 0..3
  const int quad = lane >> 4;
  const int l16  = lane & 15;
  const int ch   = wv >> 1;       // co-half: channels [ch*16, ch*16+16)
  const int xh   = wv & 1;        // x-half:  pixels   [xh*32, xh*32+32)

  const int x0 = blockIdx.x * PT;
  const int y0 = blockIdx.y * RT;
  const int n  = blockIdx.z;

  const float* xb = x + (size_t)n * C_IN * HIWI + (size_t)y0 * WI;

  // stage one unit: global tile row gr (0..7), pixel px (0..65), ci-octet oct.
  // 8 ci-strided dword loads (per wave-instr: 16 consecutive px x 4 octets =
  // 4 x 64B aligned segments), pack to bf16, 2x ds_write_b64 at 72B pixel
  // stride (bank-minimum for b64).
  auto stage = [&](int gr, int px, int oct) {
    int gx = x0 + px;
    if (gx > WI - 1) gx = WI - 1;  // clamp last tile's halo (values unused)
    const float* xp = xb + (size_t)(oct * 8) * HIWI + gr * WI + gx;
    union { __bf16 b[8]; ushortx4 q[2]; } pk;
#pragma unroll
    for (int k = 0; k < 8; ++k)
      pk.b[k] = (__bf16)xp[k * HIWI];
    unsigned short* dst = &lds[((gr & (RBUF - 1)) * XCOLS + px) * PSTR + oct * 8];
    *reinterpret_cast<ushortx4*>(dst)     = pk.q[0];
    *reinterpret_cast<ushortx4*>(dst + 4) = pk.q[1];
  };

  // ---- prologue: stage tile rows 0..2 (3 x 264 units)
  for (int u = t; u < 3 * UNITS; u += NT) {
    const int gr  = u / UNITS;
    const int rem = u - gr * UNITS;
    stage(gr, rem >> 2, rem & 3);
  }

  // ---- A fragments: 9 coalesced 16B loads from prepped ws (L2-resident).
  // Lane holds W[co = ch*16 + l16][ci = quad*8 + j] for each tap.
  bf16x8 afrag[9];
#pragma unroll
  for (int tap = 0; tap < 9; ++tap)
    afrag[tap] = *reinterpret_cast<const bf16x8*>(ws + ((tap * 2 + ch) * 64 + lane) * 8);

  // bias: D row (m) = quad*4 + r -> co = ch*16 + quad*4 + r
  float bv[4];
#pragma unroll
  for (int r = 0; r < 4; ++r)
    bv[r] = bias[ch * 16 + quad * 4 + r];

  __syncthreads();

  const int p0     = xh * 32 + l16;    // B col n = l16, first px-group
  const int px0    = x0 + p0;          // max 448+47 = 495 < 510 -> always valid
  const int px1    = px0 + 16;
  const bool valid1 = px1 < WO;

  for (int row = 0; row < RT; ++row) {
    // stage tile row row+3 into slot (row+3)&3 (not read by compute(row));
    // loads issue early, latency hides under this row's MFMAs.
    if (row < RT - 1) {
      stage(row + 3, t >> 2, t & 3);
      if (t < UNITS - NT) stage(row + 3, (t + NT) >> 2, (t + NT) & 3);
    }

    floatx4 acc0 = {bv[0], bv[1], bv[2], bv[3]};
    floatx4 acc1 = {bv[0], bv[1], bv[2], bv[3]};
#pragma unroll
    for (int ky = 0; ky < 3; ++ky)
#pragma unroll
      for (int kx = 0; kx < 3; ++kx) {
        // B: lane holds X[ci = quad*8 + j][pixel] ; two px-groups per wave.
        // 72B stride is 8B-aligned only -> two b64 halves (bank-minimum).
        const int base0 = (((row + ky) & (RBUF - 1)) * XCOLS + p0 + kx) * PSTR + quad * 8;
        union { bf16x8 v; bf16x4 h[2]; } bf0, bf1;
        bf0.h[0] = *reinterpret_cast<const bf16x4*>(&lds[base0]);
        bf0.h[1] = *reinterpret_cast<const bf16x4*>(&lds[base0 + 4]);
        bf1.h[0] = *reinterpret_cast<const bf16x4*>(&lds[base0 + 16 * PSTR]);
        bf1.h[1] = *reinterpret_cast<const bf16x4*>(&lds[base0 + 16 * PSTR + 4]);
        acc0 = __builtin_amdgcn_mfma_f32_16x16x32_bf16(afrag[ky * 3 + kx], bf0.v, acc0, 0, 0, 0);
        acc1 = __builtin_amdgcn_mfma_f32_16x16x32_bf16(afrag[ky * 3 + kx], bf1.v, acc1, 0, 0, 0);
      }

    float* op = out + ((size_t)(n * C_OUT + ch * 16 + quad * 4) * HO + (y0 + row)) * WO;
#pragma unroll
    for (int r = 0; r < 4; ++r) {
      op[r * (HO * WO) + px0] = acc0[r];            // co = ch*16 + quad*4 + r
      if (valid1) op[r * (HO * WO) + px1] = acc1[r];
    }

    __syncthreads();  // slot (row+3)&3 ready; slot row&3 free to overwrite
  }
}

extern "C" void kernel_launch(void* const* d_in, const int* in_sizes, int n_in,
                              void* d_out, int out_size, void* d_ws, size_t ws_size,
                              hipStream_t stream) {
  const float* x    = (const float*)d_in[0];
  const float* w    = (const float*)d_in[1];
  const float* bias = (const float*)d_in[2];
  float* out        = (float*)d_out;
  __bf16* ws        = (__bf16*)d_ws;          // needs 18432 B

  conv_wprep<<<dim3(1), 256, 0, stream>>>(w, ws);

  dim3 grid(WI / PT, HO / RT, NI);  // 8 x 85 x 16 = 10880 blocks, 256 threads
  conv3x3_mfma<<<grid, NT, 0, stream>>>(x, ws, bias, out);
}

// Round 5
// 1014.699 us; speedup vs baseline: 1.3998x; 1.0126x over previous
//
#include <hip/hip_runtime.h>

// 3x3 stride-1 VALID conv, NCHW fp32 in/out, bf16 MFMA implicit GEMM.
// N=16, Cin=Cout=32, 512x512 -> 510x510.
// D[m=co][n=pixel], K=ci (32 = one MFMA K), 9 taps accumulate.
// Structure = R1 best (378 us): RT=6/PT=64 tile, 4 waves, afrag[9][2],
// single stage->barrier->compute. This round changes ONLY the staging:
// dwordx4 global loads (16B/lane, 4x fewer load instrs / 4x outstanding
// bytes) + in-quad 4x4 lane transpose (shfl_xor 1,2) -> one conflict-free
// ds_write_b64 per unit at the proven lane-linear 72B stride; depth-6
// software pipeline keeps 6 loads in flight per thread.

namespace {
constexpr int NI    = 16;
constexpr int C_IN  = 32;
constexpr int HI    = 512;
constexpr int WI    = 512;
constexpr int C_OUT = 32;
constexpr int HO    = 510;
constexpr int WO    = 510;

constexpr int RT    = 6;        // output rows per block (510/6 = 85 exact)
constexpr int PT    = 64;       // output x-pixels per block
constexpr int XROWS = RT + 2;   // 8 staged input rows
constexpr int XCOLS = 68;       // 17 x4-groups (need 66, stage 68)
constexpr int PSTR  = 36;       // shorts per pixel (72B stride, measured conflict-free)
constexpr int HIWI  = HI * WI;
constexpr int NPASS = 17;       // staging passes: 8 rows x 8 ci-quads x 17 x4 / 64 groups
constexpr int PDEPTH = 6;       // staging software-pipeline depth
}

typedef __attribute__((ext_vector_type(4))) float  floatx4;
typedef __attribute__((ext_vector_type(8))) __bf16 bf16x8;
typedef __attribute__((ext_vector_type(4))) __bf16 bf16x4;
typedef __attribute__((ext_vector_type(4))) unsigned short ushortx4;

// ---- weight prep: w [co][ci][3][3] f32 -> ws bf16 A-fragments [tap][h][lane][j]
// lane = quad*16 + l16; element j: co = h*16 + l16, ci = quad*8 + j.
__global__ void conv_wprep(const float* __restrict__ w, __bf16* __restrict__ ws) {
  const int t = threadIdx.x;
  for (int i = t; i < 9 * 2 * 64 * 8; i += 256) {
    const int j    = i & 7;
    const int lane = (i >> 3) & 63;
    const int h    = (i >> 9) & 1;
    const int tap  = i >> 10;
    const int co   = h * 16 + (lane & 15);
    const int ci   = (lane >> 4) * 8 + j;
    ws[i] = (__bf16)w[(co * C_IN + ci) * 9 + tap];
  }
}

__global__ __launch_bounds__(256, 3)
void conv3x3_mfma(const float* __restrict__ x, const __bf16* __restrict__ ws,
                  const float* __restrict__ bias, float* __restrict__ out) {
  __shared__ __align__(16) unsigned short lds[XROWS * XCOLS * PSTR];  // 39168 B

  const int t    = threadIdx.x;
  const int lane = t & 63;
  const int wv   = t >> 6;
  const int quad = lane >> 4;
  const int l16  = lane & 15;
  const int q    = t & 3;         // lane-in-quad for staging transpose

  const int x0 = blockIdx.x * PT;
  const int y0 = blockIdx.y * RT;
  const int n  = blockIdx.z;

  const float* xb = x + (size_t)n * C_IN * HIWI + (size_t)y0 * WI;

  // ---- staging: unit = 4-lane quad loads a 4px x 4ci block.
  // group gid -> (row, c4, x4), x4 innermost so a wave's 16 groups give
  // 4 contiguous 256B segments per load instr. Lane q holds ci=c4*4+q,
  // px = 4*x4..+3 (floatx4). After 4x4 transpose lane q holds px=4*x4+q,
  // ci = c4*4..+3 -> one ds_write_b64 at lane-linear 72B stride (conflict-free).
  auto addr_of = [&](int p) -> const float* {
    const int gid = p * 64 + (t >> 2);
    const int x4  = gid % 17;
    const int rc  = gid / 17;
    const int c4  = rc & 7;
    const int row = rc >> 3;
    int gx = x0 + x4 * 4;
    if (gx > WI - 4) gx = WI - 4;   // clamp last tile's halo (values unused)
    return xb + (size_t)(c4 * 4 + q) * HIWI + row * WI + gx;
  };

  floatx4 vb[PDEPTH];
#pragma unroll
  for (int p = 0; p < PDEPTH; ++p)
    vb[p] = *reinterpret_cast<const floatx4*>(addr_of(p));

#pragma unroll
  for (int p = 0; p < NPASS; ++p) {
    const floatx4 v = vb[p % PDEPTH];
    if (p + PDEPTH < NPASS)
      vb[p % PDEPTH] = *reinterpret_cast<const floatx4*>(addr_of(p + PDEPTH));

    // 4x4 transpose across the quad: M[i][j] = v[j] on lane i.
    // step 1 (xor 1): a[j] = M[(i&2)|(j&1)][(j&2)|(i&1)]
    const float sA = (q & 1) ? v.x : v.y;
    const float rA = __shfl_xor(sA, 1);
    const float a0 = (q & 1) ? rA : v.x;
    const float a1 = (q & 1) ? v.y : rA;
    const float sB = (q & 1) ? v.z : v.w;
    const float rB = __shfl_xor(sB, 1);
    const float a2 = (q & 1) ? rB : v.z;
    const float a3 = (q & 1) ? v.w : rB;
    // step 2 (xor 2): w[j] = M[j][i]
    const float sC = (q & 2) ? a0 : a2;
    const float rC = __shfl_xor(sC, 2);
    const float w0 = (q & 2) ? rC : a0;
    const float w2 = (q & 2) ? a2 : rC;
    const float sD = (q & 2) ? a1 : a3;
    const float rD = __shfl_xor(sD, 2);
    const float w1 = (q & 2) ? rD : a1;
    const float w3 = (q & 2) ? a3 : rD;

    const int gid = p * 64 + (t >> 2);
    const int x4  = gid % 17;
    const int rc  = gid / 17;
    const int c4  = rc & 7;
    const int row = rc >> 3;
    const int px  = x4 * 4 + q;

    union { __bf16 b[4]; ushortx4 u; } pk;
    pk.b[0] = (__bf16)w0; pk.b[1] = (__bf16)w1;
    pk.b[2] = (__bf16)w2; pk.b[3] = (__bf16)w3;
    *reinterpret_cast<ushortx4*>(&lds[(row * XCOLS + px) * PSTR + c4 * 4]) = pk.u;
  }

  // ---- A fragments: 18 coalesced 16B loads from prepped ws (L2-resident)
  bf16x8 afrag[9][2];
#pragma unroll
  for (int tap = 0; tap < 9; ++tap)
#pragma unroll
    for (int h = 0; h < 2; ++h)
      afrag[tap][h] = *reinterpret_cast<const bf16x8*>(ws + ((tap * 2 + h) * 64 + lane) * 8);

  // bias per accumulator register: D row (m=co) = quad*4 + r (+16 for second half)
  float b0[4], b1[4];
#pragma unroll
  for (int r = 0; r < 4; ++r) {
    b0[r] = bias[quad * 4 + r];
    b1[r] = bias[quad * 4 + r + 16];
  }

  __syncthreads();

  const int pbase  = wv * 16 + l16;   // B-fragment column n = l16
  const int px     = x0 + pbase;
  const bool valid = px < WO;

  for (int row = 0; row < RT; ++row) {
    floatx4 acc0 = {b0[0], b0[1], b0[2], b0[3]};
    floatx4 acc1 = {b1[0], b1[1], b1[2], b1[3]};
#pragma unroll
    for (int ky = 0; ky < 3; ++ky)
#pragma unroll
      for (int kx = 0; kx < 3; ++kx) {
        // B: lane holds X[ci = quad*8 + j][pixel = pbase + kx] at row row+ky.
        // 72B stride is 8B-aligned only -> read as two b64 halves (bank-minimum).
        union { bf16x8 v; bf16x4 h[2]; } bf;
        const int base = ((row + ky) * XCOLS + pbase + kx) * PSTR + quad * 8;
        bf.h[0] = *reinterpret_cast<const bf16x4*>(&lds[base]);
        bf.h[1] = *reinterpret_cast<const bf16x4*>(&lds[base + 4]);
        acc0 = __builtin_amdgcn_mfma_f32_16x16x32_bf16(afrag[ky * 3 + kx][0], bf.v, acc0, 0, 0, 0);
        acc1 = __builtin_amdgcn_mfma_f32_16x16x32_bf16(afrag[ky * 3 + kx][1], bf.v, acc1, 0, 0, 0);
      }
    if (valid) {
      float* op = out + ((size_t)(n * C_OUT + quad * 4) * HO + (y0 + row)) * WO + px;
#pragma unroll
      for (int r = 0; r < 4; ++r) {
        op[r * (HO * WO)]        = acc0[r];   // co = quad*4 + r
        op[(16 + r) * (HO * WO)] = acc1[r];   // co = 16 + quad*4 + r
      }
    }
  }
}

extern "C" void kernel_launch(void* const* d_in, const int* in_sizes, int n_in,
                              void* d_out, int out_size, void* d_ws, size_t ws_size,
                              hipStream_t stream) {
  const float* x    = (const float*)d_in[0];
  const float* w    = (const float*)d_in[1];
  const float* bias = (const float*)d_in[2];
  float* out        = (float*)d_out;
  __bf16* ws        = (__bf16*)d_ws;          // needs 18432 B

  conv_wprep<<<dim3(1), 256, 0, stream>>>(w, ws);

  dim3 grid(WI / PT, HO / RT, NI);  // 8 x 85 x 16 = 10880 blocks, 256 threads
  conv3x3_mfma<<<grid, 256, 0, stream>>>(x, ws, bias, out);
}

// Round 6
// 1008.388 us; speedup vs baseline: 1.4085x; 1.0063x over previous
//
#include <hip/hip_runtime.h>

// 3x3 stride-1 VALID conv, NCHW fp32 in/out, bf16 MFMA implicit GEMM.
// N=16, Cin=Cout=32, 512x512 -> 510x510.
// D[m=co][n=pixel], K=ci (32 = one MFMA K), 9 taps accumulate.
// R6: BARRIER-FREE per-wave pipeline. Wave wv owns px window
// [wv*16, wv*16+18) and a private LDS region (4-row ring, 18px x 36-short
// stride). Per row: issue 9 global loads for row+3 -> compute row
// (18 MFMA) -> cvt+ds_write row+3 -> store row. Loads stay in flight
// across the whole compute phase (no __syncthreads anywhere), fixing the
// bursty-read pattern that capped R1/R4/R5 at ~2.8 TB/s regardless of
// occupancy/load-width. 2-px window overlap between waves refetches via
// L2 only. __launch_bounds__(256,3): 170-reg budget, no spill risk.

namespace {
constexpr int NI    = 16;
constexpr int C_IN  = 32;
constexpr int HI    = 512;
constexpr int WI    = 512;
constexpr int C_OUT = 32;
constexpr int HO    = 510;
constexpr int WO    = 510;

constexpr int RT    = 6;        // output rows per block (510/6 = 85 exact)
constexpr int PT    = 64;       // output x-pixels per block (4 waves x 16)
constexpr int WPX   = 18;       // staged px per wave (16 + 2 halo)
constexpr int SLOTS = 4;        // per-wave LDS row ring
constexpr int PSTR  = 36;       // shorts per pixel (72B stride, proven conflict-free)
constexpr int SLOTW = WPX * PSTR;          // 648 shorts per (wave,row-slot)
constexpr int WREG  = SLOTS * SLOTW;       // 2592 shorts per wave region
constexpr int HIWI  = HI * WI;
}

typedef __attribute__((ext_vector_type(4))) float  floatx4;
typedef __attribute__((ext_vector_type(8))) __bf16 bf16x8;
typedef __attribute__((ext_vector_type(4))) __bf16 bf16x4;

// ---- weight prep: w [co][ci][3][3] f32 -> ws bf16 A-fragments [tap][h][lane][j]
// lane = quad*16 + l16; element j: co = h*16 + l16, ci = quad*8 + j.
__global__ void conv_wprep(const float* __restrict__ w, __bf16* __restrict__ ws) {
  const int t = threadIdx.x;
  for (int i = t; i < 9 * 2 * 64 * 8; i += 256) {
    const int j    = i & 7;
    const int lane = (i >> 3) & 63;
    const int h    = (i >> 9) & 1;
    const int tap  = i >> 10;
    const int co   = h * 16 + (lane & 15);
    const int ci   = (lane >> 4) * 8 + j;
    ws[i] = (__bf16)w[(co * C_IN + ci) * 9 + tap];
  }
}

__global__ __launch_bounds__(256, 3)
void conv3x3_mfma(const float* __restrict__ x, const __bf16* __restrict__ ws,
                  const float* __restrict__ bias, float* __restrict__ out) {
  __shared__ __bf16 lds[4 * WREG];   // 20736 B, strictly per-wave regions

  const int t    = threadIdx.x;
  const int lane = t & 63;
  const int wv   = t >> 6;
  const int quad = lane >> 4;
  const int l16  = lane & 15;

  const int x0 = blockIdx.x * PT;
  const int y0 = blockIdx.y * RT;
  const int n  = blockIdx.z;

  const float* xn = x + (size_t)n * C_IN * HIWI;

  // ---- per-thread staging units: 9 units cover the wave's 18px x 32ci row
  // (u = j*64 + lane; px = u%18, ci = u/18 — each (px,ci) exactly once).
  // A[j]: global float offset (ci plane + clamped column); L[j]: LDS offset.
  int A[9], L[9];
#pragma unroll
  for (int j = 0; j < 9; ++j) {
    const int u  = j * 64 + lane;
    const int px = u % WPX;
    const int ci = u / WPX;
    int gx = x0 + wv * 16 + px;
    if (gx > WI - 1) gx = WI - 1;   // clamp halo at right edge (values unused)
    A[j] = ci * HIWI + gx;
    L[j] = wv * WREG + px * PSTR + ci;
  }

  // issue: 9 independent global loads for tile row gr (stay in flight).
  auto issue = [&](int gr, float (&st)[9]) {
    const float* rbase = xn + (size_t)(y0 + gr) * WI;
#pragma unroll
    for (int j = 0; j < 9; ++j) st[j] = rbase[A[j]];
  };
  // commit: cvt + scalar ds_write into ring slot gr&3 (72B lane stride: 2-way max).
  auto commit = [&](int gr, float (&st)[9]) {
    const int so = (gr & (SLOTS - 1)) * SLOTW;
#pragma unroll
    for (int j = 0; j < 9; ++j) lds[L[j] + so] = (__bf16)st[j];
  };

  // ---- prologue: rows 0..2, three buffers so all 27 loads overlap
  float s0[9], s1[9], s2[9];
  issue(0, s0); issue(1, s1); issue(2, s2);

  // ---- A fragments: 18 coalesced 16B loads from prepped ws (L2-resident)
  bf16x8 afrag[9][2];
#pragma unroll
  for (int tap = 0; tap < 9; ++tap)
#pragma unroll
    for (int h = 0; h < 2; ++h)
      afrag[tap][h] = *reinterpret_cast<const bf16x8*>(ws + ((tap * 2 + h) * 64 + lane) * 8);

  // bias per accumulator register: D row (m=co) = quad*4 + r (+16 for second half)
  float b0[4], b1[4];
#pragma unroll
  for (int r = 0; r < 4; ++r) {
    b0[r] = bias[quad * 4 + r];
    b1[r] = bias[quad * 4 + r + 16];
  }

  commit(0, s0); commit(1, s1); commit(2, s2);

  const int px     = x0 + wv * 16 + l16;   // B-fragment column n = l16
  const bool valid = px < WO;
  const int ldsw   = wv * WREG + l16 * PSTR + quad * 8;  // base of this lane's B reads

  float st[9];
#pragma unroll
  for (int row = 0; row < RT; ++row) {
    if (row < RT - 1) issue(row + 3, st);   // loads in flight across compute

    floatx4 acc0 = {b0[0], b0[1], b0[2], b0[3]};
    floatx4 acc1 = {b1[0], b1[1], b1[2], b1[3]};
#pragma unroll
    for (int ky = 0; ky < 3; ++ky)
#pragma unroll
      for (int kx = 0; kx < 3; ++kx) {
        // B: lane holds X[ci = quad*8 + j][px = wv*16 + l16 + kx] at row row+ky.
        // 72B stride, 8B-aligned -> two b64 halves (proven bank-minimum).
        const int base = ldsw + ((row + ky) & (SLOTS - 1)) * SLOTW + kx * PSTR;
        union { bf16x8 v; bf16x4 h[2]; } bf;
        bf.h[0] = *reinterpret_cast<const bf16x4*>(&lds[base]);
        bf.h[1] = *reinterpret_cast<const bf16x4*>(&lds[base + 4]);
        acc0 = __builtin_amdgcn_mfma_f32_16x16x32_bf16(afrag[ky * 3 + kx][0], bf.v, acc0, 0, 0, 0);
        acc1 = __builtin_amdgcn_mfma_f32_16x16x32_bf16(afrag[ky * 3 + kx][1], bf.v, acc1, 0, 0, 0);
      }

    if (row < RT - 1) commit(row + 3, st);  // slot (row+3)&3: not read until row+1

    if (valid) {
      float* op = out + ((size_t)(n * C_OUT + quad * 4) * HO + (y0 + row)) * WO + px;
#pragma unroll
      for (int r = 0; r < 4; ++r) {
        op[r * (HO * WO)]        = acc0[r];   // co = quad*4 + r
        op[(16 + r) * (HO * WO)] = acc1[r];   // co = 16 + quad*4 + r
      }
    }
  }
}

extern "C" void kernel_launch(void* const* d_in, const int* in_sizes, int n_in,
                              void* d_out, int out_size, void* d_ws, size_t ws_size,
                              hipStream_t stream) {
  const float* x    = (const float*)d_in[0];
  const float* w    = (const float*)d_in[1];
  const float* bias = (const float*)d_in[2];
  float* out        = (float*)d_out;
  __bf16* ws        = (__bf16*)d_ws;          // needs 18432 B

  conv_wprep<<<dim3(1), 256, 0, stream>>>(w, ws);

  dim3 grid(WI / PT, HO / RT, NI);  // 8 x 85 x 16 = 10880 blocks, 256 threads
  conv3x3_mfma<<<grid, 256, 0, stream>>>(x, ws, bias, out);
}

// Round 7
// 928.117 us; speedup vs baseline: 1.5303x; 1.0865x over previous
//
#include <hip/hip_runtime.h>

// 3x3 stride-1 VALID conv, NCHW fp32 in/out, bf16 MFMA implicit GEMM.
// N=16, Cin=Cout=32, 512x512 -> 510x510.
// D[m=co][n=pixel], K=ci (32 = one MFMA K), 9 taps accumulate.
// R7: DRAM-page-run hypothesis. All prior variants (any occupancy, any
// load width, barriered or not) cap at 2.7-2.9 TB/s; shared invariant is
// 256-264B runs per 1MB-strided plane (HBM page ~1KB -> activate-limited).
// This round: PT=256 -> 1056B read runs / 1KB write runs per plane.
// 3-slot LDS row ring (57KB, 2 blocks/CU), T14 issue/commit split staging,
// 512 threads, wave = (co-half, px-quarter), compile-time-affine offsets
// (no index arrays -> no R3-style spills).

namespace {
constexpr int NI    = 16;
constexpr int C_IN  = 32;
constexpr int HI    = 512;
constexpr int WI    = 512;
constexpr int C_OUT = 32;
constexpr int HO    = 510;
constexpr int WO    = 510;

constexpr int RT    = 6;          // output rows per block (510/6 = 85 exact)
constexpr int PT    = 256;        // output x-pixels per block (512/256 = 2)
constexpr int XCOLS = 264;        // staged px per row: 256 core + 8 halo
constexpr int PSTR  = 36;         // shorts per pixel (72B stride, proven conflict-free)
constexpr int SLOTS = 3;          // LDS row ring
constexpr int SLOTW = XCOLS * PSTR;   // 9504 shorts per row slot
constexpr int HIWI  = HI * WI;
constexpr int NT    = 512;
}

typedef __attribute__((ext_vector_type(4))) float  floatx4;
typedef __attribute__((ext_vector_type(8))) __bf16 bf16x8;
typedef __attribute__((ext_vector_type(4))) __bf16 bf16x4;

// ---- weight prep: w [co][ci][3][3] f32 -> ws bf16 A-fragments [tap][h][lane][j]
// lane = quad*16 + l16; element j: co = h*16 + l16, ci = quad*8 + j.
__global__ void conv_wprep(const float* __restrict__ w, __bf16* __restrict__ ws) {
  const int t = threadIdx.x;
  for (int i = t; i < 9 * 2 * 64 * 8; i += 256) {
    const int j    = i & 7;
    const int lane = (i >> 3) & 63;
    const int h    = (i >> 9) & 1;
    const int tap  = i >> 10;
    const int co   = h * 16 + (lane & 15);
    const int ci   = (lane >> 4) * 8 + j;
    ws[i] = (__bf16)w[(co * C_IN + ci) * 9 + tap];
  }
}

__global__ __launch_bounds__(NT, 4)
void conv3x3_mfma(const float* __restrict__ x, const __bf16* __restrict__ ws,
                  const float* __restrict__ bias, float* __restrict__ out) {
  __shared__ __bf16 lds[SLOTS * SLOTW];   // 57024 B -> 2 blocks/CU (16 waves)

  const int t    = threadIdx.x;
  const int lane = t & 63;
  const int wv   = t >> 6;        // 0..7
  const int quad = lane >> 4;
  const int l16  = lane & 15;
  const int ch   = wv >> 2;       // co-half: channels [ch*16, ch*16+16)
  const int wq   = wv & 3;        // px-quarter: pixels [wq*64, wq*64+64)

  const int x0 = blockIdx.x * PT;
  const int y0 = blockIdx.y * RT;
  const int n  = blockIdx.z;

  const float* xb = x + (size_t)n * C_IN * HIWI + (size_t)y0 * WI + x0;

  // ---- staging: 128 core units (ci, 64px-group g); wave wv owns ci band
  // [wv*4, wv*4+4) x 4 groups. Unit k: ci = wv*4 + (k>>2), g = k&3,
  // px = g*64 + lane -> per instruction 64 lanes read 256B contiguous; the
  // block touches 1056B per plane per row (page-amortized). Offsets are
  // compile-time affine in k: no index arrays (R3 spill lesson).
  const int Abase = (wv * 4) * HIWI + lane;   // + (k>>2)*HIWI + (k&3)*64
  const int Pbase = lane * PSTR + wv * 4;     // + (k&3)*64*PSTR + (k>>2)
  // halo px 256..263 (x0=0: real; x0=256: clamped, feeds only invalid outputs)
  const bool hw  = (t < 256);                 // wave-uniform (wv < 4)
  const int hci  = (t >> 3) & 31;
  const int hpx  = 256 + (t & 7);
  const int hgo  = hci * HIWI + ((x0 + hpx <= WI - 1) ? hpx : (WI - 1 - x0));
  const int hlo  = hpx * PSTR + hci;

  float buf[16];
  float hb = 0.f;

  auto issue = [&](int gr) {                  // 17 loads, stay in flight
    const float* rb = xb + gr * WI;
#pragma unroll
    for (int k = 0; k < 16; ++k)
      buf[k] = rb[Abase + (k >> 2) * HIWI + (k & 3) * 64];
    if (hw) hb = rb[hgo];
  };
  auto commit = [&](int gr) {                 // cvt + ds_write (72B lane stride)
    __bf16* s = lds + (gr % SLOTS) * SLOTW;
#pragma unroll
    for (int k = 0; k < 16; ++k)
      s[Pbase + (k & 3) * 64 * PSTR + (k >> 2)] = (__bf16)buf[k];
    if (hw) s[hlo] = (__bf16)hb;
  };

  // ---- prologue: rows 0..2, loads overlapped with afrag/bias fetches
  bf16x8 afrag[9];
  float bv[4];

  issue(0);
#pragma unroll
  for (int tap = 0; tap < 9; ++tap)   // 9 coalesced 16B loads (L2-resident)
    afrag[tap] = *reinterpret_cast<const bf16x8*>(ws + ((tap * 2 + ch) * 64 + lane) * 8);
  commit(0);
  issue(1);
#pragma unroll
  for (int r = 0; r < 4; ++r)
    bv[r] = bias[ch * 16 + quad * 4 + r];
  commit(1);
  issue(2);
  commit(2);

  __syncthreads();

  const int pxb = x0 + wq * 64 + l16;   // fragment f covers px = pxb + f*16

#pragma unroll
  for (int row = 0; row < RT; ++row) {
    if (row < RT - 1) issue(row + 3);   // T14: loads in flight across compute

    floatx4 acc[4];
#pragma unroll
    for (int f = 0; f < 4; ++f)
      acc[f] = floatx4{bv[0], bv[1], bv[2], bv[3]};

#pragma unroll
    for (int ky = 0; ky < 3; ++ky) {
      const __bf16* sl = lds + ((row + ky) % SLOTS) * SLOTW
                       + (wq * 64 + l16) * PSTR + quad * 8;
#pragma unroll
      for (int kx = 0; kx < 3; ++kx)
#pragma unroll
        for (int f = 0; f < 4; ++f) {
          // B: lane holds X[ci = quad*8 + j][px = wq*64 + f*16 + l16 + kx].
          // 72B stride, 8B-aligned -> two b64 halves (proven bank-minimum).
          const __bf16* p = sl + (f * 16 + kx) * PSTR;
          union { bf16x8 v; bf16x4 h[2]; } b;
          b.h[0] = *reinterpret_cast<const bf16x4*>(p);
          b.h[1] = *reinterpret_cast<const bf16x4*>(p + 4);
          acc[f] = __builtin_amdgcn_mfma_f32_16x16x32_bf16(afrag[ky * 3 + kx], b.v, acc[f], 0, 0, 0);
        }
    }

    // store: 1KB runs per co-plane per block-row
    float* op = out + ((size_t)(n * C_OUT + ch * 16 + quad * 4) * HO + (y0 + row)) * WO + pxb;
#pragma unroll
    for (int f = 0; f < 4; ++f) {
      if (pxb + f * 16 < WO) {
#pragma unroll
        for (int r = 0; r < 4; ++r)
          op[r * (HO * WO) + f * 16] = acc[f][r];   // co = ch*16 + quad*4 + r
      }
    }

    if (row < RT - 1) {
      __syncthreads();        // all waves done reading slot row%3
      commit(row + 3);        // overwrite it with row+3
      __syncthreads();        // publish before next row's reads
    }
  }
}

extern "C" void kernel_launch(void* const* d_in, const int* in_sizes, int n_in,
                              void* d_out, int out_size, void* d_ws, size_t ws_size,
                              hipStream_t stream) {
  const float* x    = (const float*)d_in[0];
  const float* w    = (const float*)d_in[1];
  const float* bias = (const float*)d_in[2];
  float* out        = (float*)d_out;
  __bf16* ws        = (__bf16*)d_ws;          // needs 18432 B

  conv_wprep<<<dim3(1), 256, 0, stream>>>(w, ws);

  dim3 grid(WI / PT, HO / RT, NI);  // 2 x 85 x 16 = 2720 blocks, 512 threads
  conv3x3_mfma<<<grid, NT, 0, stream>>>(x, ws, bias, out);
}

// Round 8
// 904.954 us; speedup vs baseline: 1.5695x; 1.0256x over previous
//
#include <hip/hip_runtime.h>

// 3x3 stride-1 VALID conv, NCHW fp32 in/out, bf16 MFMA implicit GEMM.
// N=16, Cin=Cout=32, 512x512 -> 510x510.
// R8: keep R7's page-friendly PT=256 tile (1KB runs per plane, the proven
// BW lever) and cut the per-row overhead three ways:
//  - ROW-REUSE: iterate input rows; each B-fragment read ONCE feeds 3
//    rotating output-row accumulators (ky=0..2) -> 3x fewer LDS reads.
//  - PSTR=40 (80B, 16B-aligned): B-frag = single ds_read_b128; staging
//    commit = single ds_write_b128 (both 2-way bank pattern = free class).
//  - ONE barrier per row (slot read at exactly one iter; publish covered
//    by the two intervening barriers before next use of that slot).
// 1024 threads (16 waves = co-half x px-eighth, f=2 frags/wave), 63.4 KB
// static LDS (3-slot ring), ~113 VGPR at __launch_bounds__(1024,4) -> no
// spill (R3 lesson: spills = +hundreds of MB scratch traffic).

namespace {
constexpr int NI    = 16;
constexpr int C_IN  = 32;
constexpr int HI    = 512;
constexpr int WI    = 512;
constexpr int C_OUT = 32;
constexpr int HO    = 510;
constexpr int WO    = 510;

constexpr int RT    = 6;          // output rows per block (510/6 = 85 exact)
constexpr int PT    = 256;        // output x-pixels per block
constexpr int XCOLS = 264;        // staged px per row: 256 core + 8 halo
constexpr int PSTR  = 40;         // shorts per pixel (80B stride, 16B aligned)
constexpr int SLOTS = 3;          // LDS row ring
constexpr int SLOTW = XCOLS * PSTR;   // 10560 shorts per row slot
constexpr int HIWI  = HI * WI;
constexpr int NT    = 1024;
}

typedef __attribute__((ext_vector_type(4))) float  floatx4;
typedef __attribute__((ext_vector_type(8))) __bf16 bf16x8;
typedef __attribute__((ext_vector_type(8))) unsigned short ushortx8;

// ---- weight prep: w [co][ci][3][3] f32 -> ws bf16 A-fragments [tap][h][lane][j]
// lane = quad*16 + l16; element j: co = h*16 + l16, ci = quad*8 + j.
__global__ void conv_wprep(const float* __restrict__ w, __bf16* __restrict__ ws) {
  const int t = threadIdx.x;
  for (int i = t; i < 9 * 2 * 64 * 8; i += 256) {
    const int j    = i & 7;
    const int lane = (i >> 3) & 63;
    const int h    = (i >> 9) & 1;
    const int tap  = i >> 10;
    const int co   = h * 16 + (lane & 15);
    const int ci   = (lane >> 4) * 8 + j;
    ws[i] = (__bf16)w[(co * C_IN + ci) * 9 + tap];
  }
}

__global__ __launch_bounds__(NT, 4)
void conv3x3_mfma(const float* __restrict__ x, const __bf16* __restrict__ ws,
                  const float* __restrict__ bias, float* __restrict__ out) {
  __shared__ __bf16 lds[SLOTS * SLOTW];   // 63360 B static

  const int t    = threadIdx.x;
  const int lane = t & 63;
  const int wv   = t >> 6;        // 0..15
  const int quad = lane >> 4;
  const int l16  = lane & 15;
  const int ch   = wv >> 3;       // co-half: channels [ch*16, ch*16+16)
  const int w8   = wv & 7;        // px window [w8*32, w8*32+32)

  const int x0 = blockIdx.x * PT;
  const int y0 = blockIdx.y * RT;
  const int n  = blockIdx.z;

  const float* xn = x + (size_t)n * C_IN * HIWI;

  // ---- staging geometry: thread t covers core px = t&255, ci octet cq = t>>8,
  // k=0..7 -> ci = cq*8+k. Per (cq,k) instruction-group: 256 consecutive px
  // = 1KB contiguous per plane (page-amortized). Commit packs 8 bf16 ->
  // single ds_write_b128 at 80B lane stride (2-way banks, free class).
  const int ps   = t & 255;
  const int cq   = t >> 8;                      // 0..3
  const int gofs = (cq * 8) * HIWI + x0 + ps;   // + k*HIWI + (y0+gr)*WI
  const int lofs = ps * PSTR + cq * 8;          // + slot*SLOTW

  // halo px 256..263 (x0=0: real; x0=256: clamped, feeds only invalid outputs)
  const bool hw  = (wv < 4);
  const int hci  = t >> 3;                      // 0..31 for t<256
  const int hpx  = 256 + (t & 7);
  int hgx = x0 + hpx; if (hgx > WI - 1) hgx = WI - 1;
  const int hgo  = hci * HIWI + hgx;
  const int hlo  = hpx * PSTR + hci;

  auto issue = [&](int gr, float (&b)[8], float& h) {   // 8(+1) loads, in flight
    const float* rb = xn + (size_t)(y0 + gr) * WI;
#pragma unroll
    for (int k = 0; k < 8; ++k) b[k] = rb[gofs + k * HIWI];
    if (hw) h = rb[hgo];
  };
  auto commit = [&](int slot, float (&b)[8], float h) { // cvt + one b128 write
    __bf16* s = lds + slot * SLOTW;
    union { __bf16 bb[8]; ushortx8 u; } pk;
#pragma unroll
    for (int k = 0; k < 8; ++k) pk.bb[k] = (__bf16)b[k];
    *reinterpret_cast<ushortx8*>(s + lofs) = pk.u;      // (ps*80+cq*16)B: 16B aligned
    if (hw) s[hlo] = (__bf16)h;
  };

  // ---- prologue: rows 0..2 staged with overlapped loads
  {
    float p0[8], p1[8], p2[8];
    float h0 = 0.f, h1 = 0.f, h2 = 0.f;
    issue(0, p0, h0); issue(1, p1, h1); issue(2, p2, h2);
    commit(0, p0, h0); commit(1, p1, h1); commit(2, p2, h2);
  }

  // ---- A fragments: 9 coalesced 16B loads from prepped ws (L2-resident).
  bf16x8 afrag[9];
#pragma unroll
  for (int tap = 0; tap < 9; ++tap)
    afrag[tap] = *reinterpret_cast<const bf16x8*>(ws + ((tap * 2 + ch) * 64 + lane) * 8);

  float bv[4];
#pragma unroll
  for (int r = 0; r < 4; ++r)
    bv[r] = bias[ch * 16 + quad * 4 + r];

  __syncthreads();

  const int pxb = x0 + w8 * 32 + l16;   // fragment f covers px = pxb + f*16
  floatx4 acc[3][2];                    // rotating: output row o lives in acc[o%3]
  float buf[8]; float hb = 0.f;

#pragma unroll
  for (int ir = 0; ir < RT + 2; ++ir) {           // input rows y0+0 .. y0+7
    if (ir + 3 < RT + 2) issue(ir + 3, buf, hb);  // loads in flight across compute

    if (ir < RT) {                                // output row ir starts here
#pragma unroll
      for (int f = 0; f < 2; ++f)
        acc[ir % 3][f] = floatx4{bv[0], bv[1], bv[2], bv[3]};
    }

    // read this input row's 6 B-fragments ONCE (single b128 each)
    bf16x8 bf[2][3];
    const __bf16* sl = lds + (ir % SLOTS) * SLOTW + (w8 * 32 + l16) * PSTR + quad * 8;
#pragma unroll
    for (int f = 0; f < 2; ++f)
#pragma unroll
      for (int kx = 0; kx < 3; ++kx)
        bf[f][kx] = *reinterpret_cast<const bf16x8*>(sl + (f * 16 + kx) * PSTR);

    // each fragment feeds up to 3 output rows (ky = ir - o)
#pragma unroll
    for (int ky = 0; ky < 3; ++ky) {
      const int o = ir - ky;
      if (o < 0 || o >= RT) continue;
#pragma unroll
      for (int kx = 0; kx < 3; ++kx)
#pragma unroll
        for (int f = 0; f < 2; ++f)
          acc[o % 3][f] = __builtin_amdgcn_mfma_f32_16x16x32_bf16(
              afrag[ky * 3 + kx], bf[f][kx], acc[o % 3][f], 0, 0, 0);
    }

    if (ir >= 2) {   // output row o = ir-2 complete; 1KB runs per co-plane
      const int o = ir - 2;
      float* op = out + ((size_t)(n * C_OUT + ch * 16 + quad * 4) * HO + (y0 + o)) * WO + pxb;
#pragma unroll
      for (int f = 0; f < 2; ++f) {
        if (pxb + f * 16 < WO) {
#pragma unroll
          for (int r = 0; r < 4; ++r)
            op[r * (HO * WO) + f * 16] = acc[o % 3][f][r];   // co = ch*16+quad*4+r
        }
      }
    }

    __syncthreads();                 // all waves done reading slot ir%3
    if (ir + 3 < RT + 2)
      commit(ir % SLOTS, buf, hb);   // row ir+3 -> slot (ir+3)%3 == ir%3;
                                     // published by the next two barriers
  }
}

extern "C" void kernel_launch(void* const* d_in, const int* in_sizes, int n_in,
                              void* d_out, int out_size, void* d_ws, size_t ws_size,
                              hipStream_t stream) {
  const float* x    = (const float*)d_in[0];
  const float* w    = (const float*)d_in[1];
  const float* bias = (const float*)d_in[2];
  float* out        = (float*)d_out;
  __bf16* ws        = (__bf16*)d_ws;          // needs 18432 B

  conv_wprep<<<dim3(1), 256, 0, stream>>>(w, ws);

  dim3 grid(WI / PT, HO / RT, NI);  // 2 x 85 x 16 = 2720 blocks, 1024 threads
  conv3x3_mfma<<<grid, NT, 0, stream>>>(x, ws, bias, out);
}